// Round 3
// baseline (483.037 us; speedup 1.0000x reference)
//
#include <hip/hip_runtime.h>
#include <stdint.h>

#define DIM 2048
#define SEQ 2048
#define NHEADS 16
#define HDIM 128
#define BSZ 2
#define ROWS (BSZ*SEQ)   // 4096

typedef uint16_t u16;
typedef __attribute__((ext_vector_type(8))) short bf16x8;
typedef __attribute__((ext_vector_type(4))) float fx4;
typedef __attribute__((ext_vector_type(4))) uint16_t u16x4;

typedef const __attribute__((address_space(1))) uint32_t* gp_t;
typedef __attribute__((address_space(3))) uint32_t* lp_t;
#define GLL16(g, l) __builtin_amdgcn_global_load_lds((gp_t)(g), (lp_t)(l), 16, 0, 0)

__device__ inline u16 f2bf(float f) {
  union { float f; uint32_t u; } v; v.f = f;
  uint32_t u = v.u;
  u += 0x7FFFu + ((u >> 16) & 1u);   // RNE
  return (u16)(u >> 16);
}
__device__ inline float bf2f(u16 h) {
  union { uint32_t u; float f; } v; v.u = ((uint32_t)h) << 16;
  return v.f;
}

// ---------------------------------------------------------------- fused convert fp32 -> bf16
// dst regions are contiguous in ws: [x (XN), wq, wk, wv, wo (WN each)]
__global__ __launch_bounds__(256) void cvt5_kernel(const float* __restrict__ sx,
    const float* __restrict__ s1, const float* __restrict__ s2,
    const float* __restrict__ s3, const float* __restrict__ s4,
    u16* __restrict__ dst) {
  const int XC = (ROWS * DIM) / 4;         // 2097152 x-chunks
  const int WC = (DIM * DIM) / 4;          // 1048576 = 2^20 per weight
  int i = blockIdx.x * 256 + threadIdx.x;
  const float* src;
  int off;
  if (i < XC) { src = sx; off = i; }
  else {
    int t = i - XC;
    int w = t >> 20;
    off = t & (WC - 1);
    src = (w == 0) ? s1 : (w == 1) ? s2 : (w == 2) ? s3 : s4;
  }
  fx4 f = *(const fx4*)(src + (size_t)off * 4);
  u16x4 o;
  o[0] = f2bf(f[0]); o[1] = f2bf(f[1]); o[2] = f2bf(f[2]); o[3] = f2bf(f[3]);
  *(u16x4*)(dst + (size_t)i * 4) = o;
}

// ---------------------------------------------------------------- GEMM core (m97 pattern)
__device__ inline void gemm128_core(const u16* __restrict__ A, const u16* __restrict__ B,
                                    u16 (&As)[128][32], u16 (&Bs)[128][32],
                                    fx4 (&acc)[4][4], int M0, int N0) {
  const int tid  = threadIdx.x;
  const int lane = tid & 63;
  const int wave = tid >> 6;
  const int wm = (wave >> 1) * 64;
  const int wn = (wave & 1) * 64;
  const int l16 = lane & 15;
  const int q8  = (lane >> 4) * 8;
#pragma unroll
  for (int tm = 0; tm < 4; ++tm)
#pragma unroll
    for (int tn = 0; tn < 4; ++tn) acc[tm][tn] = fx4{0.f, 0.f, 0.f, 0.f};

  const int wrow = wave * 32;
  const size_t laneA = (size_t)(M0 + wrow + (lane >> 2)) * DIM + (lane & 3) * 8;
  const size_t laneB = (size_t)(N0 + wrow + (lane >> 2)) * DIM + (lane & 3) * 8;

  for (int k0 = 0; k0 < DIM; k0 += 32) {
    __syncthreads();
    GLL16(A + laneA + k0,            &As[wrow][0]);
    GLL16(A + laneA + 16 * DIM + k0, &As[wrow + 16][0]);
    GLL16(B + laneB + k0,            &Bs[wrow][0]);
    GLL16(B + laneB + 16 * DIM + k0, &Bs[wrow + 16][0]);
    __syncthreads();
    bf16x8 af[4], bfr[4];
#pragma unroll
    for (int t = 0; t < 4; ++t) {
      af[t]  = *(const bf16x8*)&As[wm + t * 16 + l16][q8];
      bfr[t] = *(const bf16x8*)&Bs[wn + t * 16 + l16][q8];
    }
#pragma unroll
    for (int tm = 0; tm < 4; ++tm)
#pragma unroll
      for (int tn = 0; tn < 4; ++tn)
        acc[tm][tn] = __builtin_amdgcn_mfma_f32_16x16x32_bf16(af[tm], bfr[tn], acc[tm][tn], 0, 0, 0);
  }
}

// QKV projection with RoPE fused into the epilogue for z=0 (Q) and z=1 (K).
__global__ __launch_bounds__(256) void gemm_qkv(const u16* __restrict__ A,
    const u16* __restrict__ B0, const u16* __restrict__ B1, const u16* __restrict__ B2,
    u16* __restrict__ C0, u16* __restrict__ C1, u16* __restrict__ C2,
    const float* __restrict__ fcos, const float* __restrict__ fsin) {
  __shared__ __align__(16) u16 As[128][32];
  __shared__ __align__(16) u16 Bs[128][32];
  const u16* B = (blockIdx.z == 0) ? B0 : (blockIdx.z == 1) ? B1 : B2;
  u16* C       = (blockIdx.z == 0) ? C0 : (blockIdx.z == 1) ? C1 : C2;
  const int M0 = blockIdx.y * 128, N0 = blockIdx.x * 128;
  fx4 acc[4][4];
  gemm128_core(A, B, As, Bs, acc, M0, N0);
  const int lane = threadIdx.x & 63, wave = threadIdx.x >> 6;
  const int wm = (wave >> 1) * 64, wn = (wave & 1) * 64;
  const int l16 = lane & 15, quad = lane >> 4;
  if (blockIdx.z < 2) {
    // RoPE in fp32 before rounding; col pairs live in adjacent lanes.
    const bool odd = l16 & 1;
#pragma unroll
    for (int tm = 0; tm < 4; ++tm)
#pragma unroll
      for (int tn = 0; tn < 4; ++tn) {
        int col = N0 + wn + tn * 16 + l16;
        int p = (col & 127) >> 1;
#pragma unroll
        for (int r = 0; r < 4; ++r) {
          int row = M0 + wm + tm * 16 + quad * 4 + r;
          int s_pos = row & (SEQ - 1);
          float val = acc[tm][tn][r];
          float partner = __shfl_xor(val, 1);
          float c = fcos[s_pos * 64 + p], sn = fsin[s_pos * 64 + p];
          float a = odd ? partner : val;
          float bb = odd ? val : partner;
          float outv = odd ? (a * sn + bb * c) : (a * c - bb * sn);
          C[(size_t)row * DIM + col] = f2bf(outv);
        }
      }
  } else {
#pragma unroll
    for (int tm = 0; tm < 4; ++tm)
#pragma unroll
      for (int tn = 0; tn < 4; ++tn)
#pragma unroll
        for (int r = 0; r < 4; ++r) {
          size_t row = (size_t)(M0 + wm + tm * 16 + quad * 4 + r);
          size_t col = (size_t)(N0 + wn + tn * 16 + l16);
          C[row * DIM + col] = f2bf(acc[tm][tn][r]);
        }
  }
}

__global__ __launch_bounds__(256) void gemm_out(const u16* __restrict__ A,
                                                const u16* __restrict__ B,
                                                float* __restrict__ C) {
  __shared__ __align__(16) u16 As[128][32];
  __shared__ __align__(16) u16 Bs[128][32];
  const int M0 = blockIdx.y * 128, N0 = blockIdx.x * 128;
  fx4 acc[4][4];
  gemm128_core(A, B, As, Bs, acc, M0, N0);
  const int lane = threadIdx.x & 63, wave = threadIdx.x >> 6;
  const int wm = (wave >> 1) * 64, wn = (wave & 1) * 64;
  const int l16 = lane & 15, quad = lane >> 4;
#pragma unroll
  for (int tm = 0; tm < 4; ++tm)
#pragma unroll
    for (int tn = 0; tn < 4; ++tn)
#pragma unroll
      for (int r = 0; r < 4; ++r) {
        size_t row = (size_t)(M0 + wm + tm * 16 + quad * 4 + r);
        size_t col = (size_t)(N0 + wn + tn * 16 + l16);
        C[row * DIM + col] = acc[tm][tn][r];
      }
}

// ---------------------------------------------------------------- V transpose
__global__ __launch_bounds__(256) void vtrans_kernel(const u16* __restrict__ v,
                                                     u16* __restrict__ vtg) {
  __shared__ __align__(16) u16 T[128][72];
  const int tid = threadIdx.x;
  const int s0 = blockIdx.x * 64;
  const int bh = blockIdx.y;
  const int b = bh >> 4, h = bh & 15;
  const size_t vb = ((size_t)b * SEQ + s0) * DIM + h * HDIM;
#pragma unroll
  for (int i = 0; i < 4; ++i) {
    int c = i * 256 + tid;
    int s = c >> 4;
    int d0 = (c & 15) * 8;
    bf16x8 x = *(const bf16x8*)(v + vb + (size_t)s * DIM + d0);
#pragma unroll
    for (int j = 0; j < 8; ++j) T[d0 + j][s] = (u16)x[j];
  }
  __syncthreads();
  const size_t ob = ((size_t)bh * HDIM) * SEQ + s0;
#pragma unroll
  for (int i = 0; i < 4; ++i) {
    int c = i * 256 + tid;
    int d = c >> 3;
    int s8 = (c & 7) * 8;
    *(bf16x8*)(vtg + ob + (size_t)d * SEQ + s8) = *(const bf16x8*)&T[d][s8];
  }
}

// ---------------------------------------------------------------- flash attention
// Br=128 (4 waves x 32 q-rows, 2 m-tiles each), Bc=64. Register prefetch dbuf.
// Complementary-qt pairing: blocks i and i+256 sum to 34 iterations.
__global__ __launch_bounds__(256, 2) void attn_kernel(const u16* __restrict__ qm,
                                                      const u16* __restrict__ km,
                                                      const u16* __restrict__ vtg,
                                                      u16* __restrict__ ao) {
  __shared__ __align__(16) u16 Ks[64][136];
  __shared__ __align__(16) u16 Vt[128][72];
  __shared__ __align__(16) u16 Ps[4][32][72];
  const int tid = threadIdx.x;
  const int lane = tid & 63, wave = tid >> 6;
  const int l16 = lane & 15, quad = lane >> 4;
  const int idx = blockIdx.x;
  const int bh = idx & 31;
  const int j = idx >> 5;                  // 0..15
  const int qt = (j < 8) ? (15 - j) : (j - 8);
  const int b = bh >> 4, h = bh & 15;
  const int q0 = qt * 128;
  const size_t brow = (size_t)b * SEQ;
  const int hc = h * HDIM;
  const size_t vbase = (size_t)bh * HDIM * SEQ;
  const int nkt = 2 * qt + 2;

  bf16x8 aq[2][4];
#pragma unroll
  for (int mt = 0; mt < 2; ++mt) {
    size_t qbase = (brow + q0 + wave * 32 + mt * 16 + l16) * DIM + hc;
#pragma unroll
    for (int dc = 0; dc < 4; ++dc)
      aq[mt][dc] = *(const bf16x8*)(qm + qbase + dc * 32 + quad * 8);
  }
  fx4 o[16];
#pragma unroll
  for (int i = 0; i < 16; ++i) o[i] = fx4{0.f, 0.f, 0.f, 0.f};
  float mr[2][4], lr[2][4];
#pragma unroll
  for (int mt = 0; mt < 2; ++mt)
#pragma unroll
    for (int r = 0; r < 4; ++r) { mr[mt][r] = -3e38f; lr[mt][r] = 0.f; }

  bf16x8 kreg[4], vreg[4];
#pragma unroll
  for (int i = 0; i < 4; ++i) {
    int c = i * 256 + tid;
    kreg[i] = *(const bf16x8*)(km + (brow + (c >> 4)) * DIM + hc + (c & 15) * 8);
    vreg[i] = *(const bf16x8*)(vtg + vbase + (size_t)(c >> 3) * SEQ + (c & 7) * 8);
  }

  for (int kt = 0; kt < nkt; ++kt) {
    __syncthreads();
#pragma unroll
    for (int i = 0; i < 4; ++i) {
      int c = i * 256 + tid;
      *(bf16x8*)&Ks[c >> 4][(c & 15) * 8] = kreg[i];
      *(bf16x8*)&Vt[c >> 3][(c & 7) * 8] = vreg[i];
    }
    __syncthreads();
    if (kt + 1 < nkt) {
      const int kv1 = (kt + 1) * 64;
#pragma unroll
      for (int i = 0; i < 4; ++i) {
        int c = i * 256 + tid;
        kreg[i] = *(const bf16x8*)(km + (brow + kv1 + (c >> 4)) * DIM + hc + (c & 15) * 8);
        vreg[i] = *(const bf16x8*)(vtg + vbase + (size_t)(c >> 3) * SEQ + kv1 + (c & 7) * 8);
      }
    }
    // S = Q K^T; K frags shared across both m-tiles
    fx4 s[2][4];
#pragma unroll
    for (int tn = 0; tn < 4; ++tn) {
      fx4 a0 = fx4{0.f, 0.f, 0.f, 0.f}, a1 = fx4{0.f, 0.f, 0.f, 0.f};
#pragma unroll
      for (int dc = 0; dc < 4; ++dc) {
        bf16x8 bk = *(const bf16x8*)&Ks[tn * 16 + l16][dc * 32 + quad * 8];
        a0 = __builtin_amdgcn_mfma_f32_16x16x32_bf16(aq[0][dc], bk, a0, 0, 0, 0);
        a1 = __builtin_amdgcn_mfma_f32_16x16x32_bf16(aq[1][dc], bk, a1, 0, 0, 0);
      }
      s[0][tn] = a0 * 0.08838834764831845f;
      s[1][tn] = a1 * 0.08838834764831845f;
    }
    // causal mask (only the last two tiles can touch the diagonal)
    if (kt >= nkt - 2) {
      const int kv0 = kt * 64;
#pragma unroll
      for (int mt = 0; mt < 2; ++mt)
#pragma unroll
        for (int tn = 0; tn < 4; ++tn) {
          int kvpos = kv0 + tn * 16 + l16;
#pragma unroll
          for (int r = 0; r < 4; ++r) {
            int qpos = q0 + wave * 32 + mt * 16 + quad * 4 + r;
            if (kvpos > qpos) s[mt][tn][r] = -1e30f;
          }
        }
    }
    // online softmax per m-tile
    float alpha[2][4];
#pragma unroll
    for (int mt = 0; mt < 2; ++mt)
#pragma unroll
      for (int r = 0; r < 4; ++r) {
        float t = fmaxf(fmaxf(s[mt][0][r], s[mt][1][r]), fmaxf(s[mt][2][r], s[mt][3][r]));
        t = fmaxf(t, __shfl_xor(t, 1));
        t = fmaxf(t, __shfl_xor(t, 2));
        t = fmaxf(t, __shfl_xor(t, 4));
        t = fmaxf(t, __shfl_xor(t, 8));
        float mnew = fmaxf(mr[mt][r], t);
        alpha[mt][r] = __expf(mr[mt][r] - mnew);
        float sm = 0.f;
#pragma unroll
        for (int tn = 0; tn < 4; ++tn) {
          float p = __expf(s[mt][tn][r] - mnew);
          s[mt][tn][r] = p;
          sm += p;
        }
        sm += __shfl_xor(sm, 1);
        sm += __shfl_xor(sm, 2);
        sm += __shfl_xor(sm, 4);
        sm += __shfl_xor(sm, 8);
        lr[mt][r] = lr[mt][r] * alpha[mt][r] + sm;
        mr[mt][r] = mnew;
      }
    // P -> per-wave LDS (C-layout -> A-layout round trip)
#pragma unroll
    for (int mt = 0; mt < 2; ++mt)
#pragma unroll
      for (int tn = 0; tn < 4; ++tn)
#pragma unroll
        for (int r = 0; r < 4; ++r)
          Ps[wave][mt * 16 + quad * 4 + r][tn * 16 + l16] = f2bf(s[mt][tn][r]);
    // rescale O
#pragma unroll
    for (int mt = 0; mt < 2; ++mt)
#pragma unroll
      for (int nt = 0; nt < 8; ++nt) {
        fx4 t = o[mt * 8 + nt];
        t[0] *= alpha[mt][0]; t[1] *= alpha[mt][1];
        t[2] *= alpha[mt][2]; t[3] *= alpha[mt][3];
        o[mt * 8 + nt] = t;
      }
    // O += P V ; V frags shared across both m-tiles
#pragma unroll
    for (int t2 = 0; t2 < 2; ++t2) {
      bf16x8 ap0 = *(const bf16x8*)&Ps[wave][l16][t2 * 32 + quad * 8];
      bf16x8 ap1 = *(const bf16x8*)&Ps[wave][16 + l16][t2 * 32 + quad * 8];
#pragma unroll
      for (int nt = 0; nt < 8; ++nt) {
        bf16x8 bv = *(const bf16x8*)&Vt[nt * 16 + l16][t2 * 32 + quad * 8];
        o[nt]     = __builtin_amdgcn_mfma_f32_16x16x32_bf16(ap0, bv, o[nt], 0, 0, 0);
        o[8 + nt] = __builtin_amdgcn_mfma_f32_16x16x32_bf16(ap1, bv, o[8 + nt], 0, 0, 0);
      }
    }
  }
  // epilogue
#pragma unroll
  for (int mt = 0; mt < 2; ++mt)
#pragma unroll
    for (int nt = 0; nt < 8; ++nt)
#pragma unroll
      for (int r = 0; r < 4; ++r) {
        float val = o[mt * 8 + nt][r] / lr[mt][r];
        size_t row = brow + q0 + wave * 32 + mt * 16 + quad * 4 + r;
        ao[row * DIM + hc + nt * 16 + l16] = f2bf(val);
      }
}

// ---------------------------------------------------------------- launch
extern "C" void kernel_launch(void* const* d_in, const int* in_sizes, int n_in,
                              void* d_out, int out_size, void* d_ws, size_t ws_size,
                              hipStream_t stream) {
  const float* x    = (const float*)d_in[0];
  const float* fcos = (const float*)d_in[2];
  const float* fsin = (const float*)d_in[3];
  const float* wq   = (const float*)d_in[5];
  const float* wk   = (const float*)d_in[6];
  const float* wv   = (const float*)d_in[7];
  const float* wo   = (const float*)d_in[8];
  float* out = (float*)d_out;

  const size_t XN = (size_t)ROWS * DIM;
  const size_t WN = (size_t)DIM * DIM;
  u16* ws  = (u16*)d_ws;
  u16* xb  = ws;
  u16* wqb = xb + XN;
  u16* wkb = wqb + WN;
  u16* wvb = wkb + WN;
  u16* wob = wvb + WN;
  u16* q   = wob + WN;
  u16* k   = q + XN;
  u16* v   = k + XN;
  u16* ao  = v + XN;
  u16* vtg = xb;   // alias: x-bf16 dead after gemm_qkv

  const int total_chunks = (int)((XN + 4 * WN) / 4);   // 6291456
  cvt5_kernel<<<total_chunks / 256, 256, 0, stream>>>(x, wq, wk, wv, wo, ws);

  gemm_qkv<<<dim3(DIM / 128, ROWS / 128, 3), 256, 0, stream>>>(xb, wqb, wkb, wvb,
                                                               q, k, v, fcos, fsin);

  vtrans_kernel<<<dim3(SEQ / 64, BSZ * NHEADS), 256, 0, stream>>>(v, vtg);

  attn_kernel<<<dim3(512), 256, 0, stream>>>(q, k, vtg, ao);

  gemm_out<<<dim3(DIM / 128, ROWS / 128), 256, 0, stream>>>(ao, wob, out);
}

// Round 4
// 414.082 us; speedup vs baseline: 1.1665x; 1.1665x over previous
//
#include <hip/hip_runtime.h>
#include <stdint.h>

#define DIM 2048
#define SEQ 2048
#define NHEADS 16
#define HDIM 128
#define BSZ 2
#define ROWS (BSZ*SEQ)   // 4096

typedef uint16_t u16;
typedef __attribute__((ext_vector_type(8))) short bf16x8;
typedef __attribute__((ext_vector_type(4))) short bf16x4;
typedef __attribute__((ext_vector_type(4))) float fx4;
typedef __attribute__((ext_vector_type(4))) uint16_t u16x4;

typedef const __attribute__((address_space(1))) uint32_t* gp_t;
typedef __attribute__((address_space(3))) uint32_t* lp_t;
#define GLL16(g, l) __builtin_amdgcn_global_load_lds((gp_t)(g), (lp_t)(l), 16, 0, 0)

__device__ inline u16 f2bf(float f) {
  union { float f; uint32_t u; } v; v.f = f;
  uint32_t u = v.u;
  u += 0x7FFFu + ((u >> 16) & 1u);   // RNE
  return (u16)(u >> 16);
}
__device__ inline float bf2f(u16 h) {
  union { uint32_t u; float f; } v; v.u = ((uint32_t)h) << 16;
  return v.f;
}

// ---------------------------------------------------------------- fused convert fp32 -> bf16
__global__ __launch_bounds__(256) void cvt5_kernel(const float* __restrict__ sx,
    const float* __restrict__ s1, const float* __restrict__ s2,
    const float* __restrict__ s3, const float* __restrict__ s4,
    u16* __restrict__ dst) {
  const int XC = (ROWS * DIM) / 4;
  const int WC = (DIM * DIM) / 4;          // 2^20
  int i = blockIdx.x * 256 + threadIdx.x;
  const float* src;
  int off;
  if (i < XC) { src = sx; off = i; }
  else {
    int t = i - XC;
    int w = t >> 20;
    off = t & (WC - 1);
    src = (w == 0) ? s1 : (w == 1) ? s2 : (w == 2) ? s3 : s4;
  }
  fx4 f = *(const fx4*)(src + (size_t)off * 4);
  u16x4 o;
  o[0] = f2bf(f[0]); o[1] = f2bf(f[1]); o[2] = f2bf(f[2]); o[3] = f2bf(f[3]);
  *(u16x4*)(dst + (size_t)i * 4) = o;
}

// ---------------------------------------------------------------- GEMM core (m97 pattern)
__device__ inline void gemm128_core(const u16* __restrict__ A, const u16* __restrict__ B,
                                    u16 (&As)[128][32], u16 (&Bs)[128][32],
                                    fx4 (&acc)[4][4], int M0, int N0) {
  const int tid  = threadIdx.x;
  const int lane = tid & 63;
  const int wave = tid >> 6;
  const int wm = (wave >> 1) * 64;
  const int wn = (wave & 1) * 64;
  const int l16 = lane & 15;
  const int q8  = (lane >> 4) * 8;
#pragma unroll
  for (int tm = 0; tm < 4; ++tm)
#pragma unroll
    for (int tn = 0; tn < 4; ++tn) acc[tm][tn] = fx4{0.f, 0.f, 0.f, 0.f};

  const int wrow = wave * 32;
  const size_t laneA = (size_t)(M0 + wrow + (lane >> 2)) * DIM + (lane & 3) * 8;
  const size_t laneB = (size_t)(N0 + wrow + (lane >> 2)) * DIM + (lane & 3) * 8;

  for (int k0 = 0; k0 < DIM; k0 += 32) {
    __syncthreads();
    GLL16(A + laneA + k0,            &As[wrow][0]);
    GLL16(A + laneA + 16 * DIM + k0, &As[wrow + 16][0]);
    GLL16(B + laneB + k0,            &Bs[wrow][0]);
    GLL16(B + laneB + 16 * DIM + k0, &Bs[wrow + 16][0]);
    __syncthreads();
    bf16x8 af[4], bfr[4];
#pragma unroll
    for (int t = 0; t < 4; ++t) {
      af[t]  = *(const bf16x8*)&As[wm + t * 16 + l16][q8];
      bfr[t] = *(const bf16x8*)&Bs[wn + t * 16 + l16][q8];
    }
#pragma unroll
    for (int tm = 0; tm < 4; ++tm)
#pragma unroll
      for (int tn = 0; tn < 4; ++tn)
        acc[tm][tn] = __builtin_amdgcn_mfma_f32_16x16x32_bf16(af[tm], bfr[tn], acc[tm][tn], 0, 0, 0);
  }
}

__global__ __launch_bounds__(256) void gemm_qkv(const u16* __restrict__ A,
    const u16* __restrict__ B0, const u16* __restrict__ B1, const u16* __restrict__ B2,
    u16* __restrict__ C0, u16* __restrict__ C1, u16* __restrict__ C2) {
  __shared__ __align__(16) u16 As[128][32];
  __shared__ __align__(16) u16 Bs[128][32];
  const u16* B = (blockIdx.z == 0) ? B0 : (blockIdx.z == 1) ? B1 : B2;
  u16* C       = (blockIdx.z == 0) ? C0 : (blockIdx.z == 1) ? C1 : C2;
  const int M0 = blockIdx.y * 128, N0 = blockIdx.x * 128;
  fx4 acc[4][4];
  gemm128_core(A, B, As, Bs, acc, M0, N0);
  const int lane = threadIdx.x & 63, wave = threadIdx.x >> 6;
  const int wm = (wave >> 1) * 64, wn = (wave & 1) * 64;
  const int l16 = lane & 15, quad = lane >> 4;
#pragma unroll
  for (int tm = 0; tm < 4; ++tm)
#pragma unroll
    for (int tn = 0; tn < 4; ++tn)
#pragma unroll
      for (int r = 0; r < 4; ++r) {
        size_t row = (size_t)(M0 + wm + tm * 16 + quad * 4 + r);
        size_t col = (size_t)(N0 + wn + tn * 16 + l16);
        C[row * DIM + col] = f2bf(acc[tm][tn][r]);
      }
}

__global__ __launch_bounds__(256) void gemm_out(const u16* __restrict__ A,
                                                const u16* __restrict__ B,
                                                float* __restrict__ C) {
  __shared__ __align__(16) u16 As[128][32];
  __shared__ __align__(16) u16 Bs[128][32];
  const int M0 = blockIdx.y * 128, N0 = blockIdx.x * 128;
  fx4 acc[4][4];
  gemm128_core(A, B, As, Bs, acc, M0, N0);
  const int lane = threadIdx.x & 63, wave = threadIdx.x >> 6;
  const int wm = (wave >> 1) * 64, wn = (wave & 1) * 64;
  const int l16 = lane & 15, quad = lane >> 4;
#pragma unroll
  for (int tm = 0; tm < 4; ++tm)
#pragma unroll
    for (int tn = 0; tn < 4; ++tn)
#pragma unroll
      for (int r = 0; r < 4; ++r) {
        size_t row = (size_t)(M0 + wm + tm * 16 + quad * 4 + r);
        size_t col = (size_t)(N0 + wn + tn * 16 + l16);
        C[row * DIM + col] = acc[tm][tn][r];
      }
}

// ---------------------------------------------------------------- RoPE (in-place on bf16 Q,K)
__global__ __launch_bounds__(256) void rope_kernel(u16* __restrict__ q, u16* __restrict__ k,
                                                   const float* __restrict__ fcos,
                                                   const float* __restrict__ fsin) {
  int idx = blockIdx.x * 256 + threadIdx.x;
  int t = idx >> 22;
  int p_all = idx & ((1 << 22) - 1);
  u16* ptr = t ? k : q;
  int row = p_all >> 10;
  int r   = p_all & 1023;
  int h   = r >> 6;
  int p   = r & 63;
  int s   = row & (SEQ - 1);
  size_t base = (size_t)row * DIM + h * HDIM + 2 * p;
  float a = bf2f(ptr[base]), b = bf2f(ptr[base + 1]);
  float c = fcos[s * 64 + p], sn = fsin[s * 64 + p];
  ptr[base]     = f2bf(a * c - b * sn);
  ptr[base + 1] = f2bf(a * sn + b * c);
}

// ---------------------------------------------------------------- V transpose
__global__ __launch_bounds__(256) void vtrans_kernel(const u16* __restrict__ v,
                                                     u16* __restrict__ vtg) {
  __shared__ __align__(16) u16 T[128][72];
  const int tid = threadIdx.x;
  const int s0 = blockIdx.x * 64;
  const int bh = blockIdx.y;
  const int b = bh >> 4, h = bh & 15;
  const size_t vb = ((size_t)b * SEQ + s0) * DIM + h * HDIM;
#pragma unroll
  for (int i = 0; i < 4; ++i) {
    int c = i * 256 + tid;
    int s = c >> 4;
    int d0 = (c & 15) * 8;
    bf16x8 x = *(const bf16x8*)(v + vb + (size_t)s * DIM + d0);
#pragma unroll
    for (int j = 0; j < 8; ++j) T[d0 + j][s] = (u16)x[j];
  }
  __syncthreads();
  const size_t ob = ((size_t)bh * HDIM) * SEQ + s0;
#pragma unroll
  for (int i = 0; i < 4; ++i) {
    int c = i * 256 + tid;
    int d = c >> 3;
    int s8 = (c & 7) * 8;
    *(bf16x8*)(vtg + ob + (size_t)d * SEQ + s8) = *(const bf16x8*)&T[d][s8];
  }
}

// ---------------------------------------------------------------- flash attention, S^T form
// S^T = K·Q^T so P^T (C-layout: col=q=lane&15, row=kv=quad*4+reg) is directly the
// B-operand of mfma_f32_16x16x16bf16_1k (n=lane&15, k=quad*4+j): PV needs NO LDS
// round-trip. O accumulates as O^T[d][q]; one LDS transpose at the end.
// Br=128 (4 waves x 2 q-tiles of 16), Bc=64.
struct SMemS { u16 Ks[64][136]; u16 Vt[128][72]; };
union SMemU { SMemS s; u16 Ot[4][32][136]; };

__global__ __launch_bounds__(256, 2) void attn_kernel(const u16* __restrict__ qm,
                                                      const u16* __restrict__ km,
                                                      const u16* __restrict__ vtg,
                                                      u16* __restrict__ ao) {
  __shared__ __align__(16) SMemU sm;
  const int tid = threadIdx.x;
  const int lane = tid & 63, wave = tid >> 6;
  const int l16 = lane & 15, quad = lane >> 4;
  const int idx = blockIdx.x;
  const int bh = idx & 31;
  const int j = idx >> 5;
  const int qt = (j < 8) ? (15 - j) : (j - 8);   // complementary pairing
  const int b = bh >> 4, h = bh & 15;
  const int q0 = qt * 128;
  const size_t brow = (size_t)b * SEQ;
  const int hc = h * HDIM;
  const size_t vbase = (size_t)bh * HDIM * SEQ;
  const int nkt = 2 * qt + 2;

  // Q as B-operand frags: B[n=q=l16][k=d=quad*8+j]
  bf16x8 aq[2][4];
#pragma unroll
  for (int nt = 0; nt < 2; ++nt) {
    size_t qbase = (brow + q0 + wave * 32 + nt * 16 + l16) * DIM + hc;
#pragma unroll
    for (int dc = 0; dc < 4; ++dc)
      aq[nt][dc] = *(const bf16x8*)(qm + qbase + dc * 32 + quad * 8);
  }
  fx4 o[2][8];   // O^T tiles: [q-tile][d-tile], C-layout col=q=l16, row=d=quad*4+r
#pragma unroll
  for (int nt = 0; nt < 2; ++nt)
#pragma unroll
    for (int dt = 0; dt < 8; ++dt) o[nt][dt] = fx4{0.f, 0.f, 0.f, 0.f};
  float mr[2] = {-3e38f, -3e38f}, lr[2] = {0.f, 0.f};   // per-lane: q = l16 of each tile

  bf16x8 kreg[4], vreg[4];
#pragma unroll
  for (int i = 0; i < 4; ++i) {
    int c = i * 256 + tid;
    kreg[i] = *(const bf16x8*)(km + (brow + (c >> 4)) * DIM + hc + (c & 15) * 8);
    vreg[i] = *(const bf16x8*)(vtg + vbase + (size_t)(c >> 3) * SEQ + (c & 7) * 8);
  }

  for (int kt = 0; kt < nkt; ++kt) {
    __syncthreads();
#pragma unroll
    for (int i = 0; i < 4; ++i) {
      int c = i * 256 + tid;
      *(bf16x8*)&sm.s.Ks[c >> 4][(c & 15) * 8] = kreg[i];
      *(bf16x8*)&sm.s.Vt[c >> 3][(c & 7) * 8] = vreg[i];
    }
    __syncthreads();
    if (kt + 1 < nkt) {
      const int kv1 = (kt + 1) * 64;
#pragma unroll
      for (int i = 0; i < 4; ++i) {
        int c = i * 256 + tid;
        kreg[i] = *(const bf16x8*)(km + (brow + kv1 + (c >> 4)) * DIM + hc + (c & 15) * 8);
        vreg[i] = *(const bf16x8*)(vtg + vbase + (size_t)(c >> 3) * SEQ + kv1 + (c & 7) * 8);
      }
    }
    // S^T = K Q^T : A = K frag (m=kv), B = Q frag (n=q). s[nt][tm]: kv=tm*16+quad*4+r, q=l16
    fx4 s[2][4];
#pragma unroll
    for (int tm = 0; tm < 4; ++tm) {
      fx4 a0 = fx4{0.f, 0.f, 0.f, 0.f}, a1 = fx4{0.f, 0.f, 0.f, 0.f};
#pragma unroll
      for (int dc = 0; dc < 4; ++dc) {
        bf16x8 kf = *(const bf16x8*)&sm.s.Ks[tm * 16 + l16][dc * 32 + quad * 8];
        a0 = __builtin_amdgcn_mfma_f32_16x16x32_bf16(kf, aq[0][dc], a0, 0, 0, 0);
        a1 = __builtin_amdgcn_mfma_f32_16x16x32_bf16(kf, aq[1][dc], a1, 0, 0, 0);
      }
      s[0][tm] = a0 * 0.08838834764831845f;
      s[1][tm] = a1 * 0.08838834764831845f;
    }
    // causal mask (only tiles touching the diagonal)
    if (kt >= nkt - 2) {
      const int kv0 = kt * 64;
#pragma unroll
      for (int nt = 0; nt < 2; ++nt) {
        int qpos = q0 + wave * 32 + nt * 16 + l16;
#pragma unroll
        for (int tm = 0; tm < 4; ++tm)
#pragma unroll
          for (int r = 0; r < 4; ++r)
            if (kv0 + tm * 16 + quad * 4 + r > qpos) s[nt][tm][r] = -1e30f;
      }
    }
    // online softmax over kv (regs + quads); q = l16 per tile
    float alpha[2];
    bf16x4 pf[2][4];
#pragma unroll
    for (int nt = 0; nt < 2; ++nt) {
      float t = -3e38f;
#pragma unroll
      for (int tm = 0; tm < 4; ++tm)
        t = fmaxf(t, fmaxf(fmaxf(s[nt][tm][0], s[nt][tm][1]),
                           fmaxf(s[nt][tm][2], s[nt][tm][3])));
      t = fmaxf(t, __shfl_xor(t, 16));
      t = fmaxf(t, __shfl_xor(t, 32));
      float mnew = fmaxf(mr[nt], t);
      alpha[nt] = __expf(mr[nt] - mnew);
      float sum = 0.f;
#pragma unroll
      for (int tm = 0; tm < 4; ++tm) {
        fx4 p;
#pragma unroll
        for (int r = 0; r < 4; ++r) {
          p[r] = __expf(s[nt][tm][r] - mnew);
          sum += p[r];
        }
        bf16x4 pb;
        pb[0] = (short)f2bf(p[0]); pb[1] = (short)f2bf(p[1]);
        pb[2] = (short)f2bf(p[2]); pb[3] = (short)f2bf(p[3]);
        pf[nt][tm] = pb;
      }
      sum += __shfl_xor(sum, 16);
      sum += __shfl_xor(sum, 32);
      lr[nt] = lr[nt] * alpha[nt] + sum;
      mr[nt] = mnew;
      // rescale O^T tiles: col=q -> alpha is lane-uniform across all 4 regs
#pragma unroll
      for (int dt = 0; dt < 8; ++dt) o[nt][dt] *= alpha[nt];
    }
    // O^T += V^T P^T : A = V^T frag (m=d, k=kv=quad*4+j, b64), B = pf (registers!)
#pragma unroll
    for (int tm = 0; tm < 4; ++tm) {
#pragma unroll
      for (int dt = 0; dt < 8; ++dt) {
        bf16x4 vf = *(const bf16x4*)&sm.s.Vt[dt * 16 + l16][tm * 16 + quad * 4];
        o[0][dt] = __builtin_amdgcn_mfma_f32_16x16x16bf16_1k(vf, pf[0][tm], o[0][dt], 0, 0, 0);
        o[1][dt] = __builtin_amdgcn_mfma_f32_16x16x16bf16_1k(vf, pf[1][tm], o[1][dt], 0, 0, 0);
      }
    }
  }
  // epilogue: O^T -> LDS transpose (reuse tile memory) -> coalesced global
  __syncthreads();   // all waves done reading Ks/Vt
#pragma unroll
  for (int nt = 0; nt < 2; ++nt) {
    float inv = 1.f / lr[nt];
#pragma unroll
    for (int dt = 0; dt < 8; ++dt) {
      fx4 v = o[nt][dt];
      u16x4 p;
      p[0] = f2bf(v[0] * inv); p[1] = f2bf(v[1] * inv);
      p[2] = f2bf(v[2] * inv); p[3] = f2bf(v[3] * inv);
      *(u16x4*)&sm.Ot[wave][nt * 16 + l16][dt * 16 + quad * 4] = p;
    }
  }
  // wave-private region: compiler's lgkmcnt ordering suffices (no barrier)
#pragma unroll
  for (int i = 0; i < 8; ++i) {
    int c = i * 64 + lane;
    int row = c >> 4;          // 0..31
    int ch = c & 15;           // 16B chunks across 128 d
    bf16x8 t = *(const bf16x8*)&sm.Ot[wave][row][ch * 8];
    *(bf16x8*)(ao + (brow + q0 + wave * 32 + row) * DIM + hc + ch * 8) = t;
  }
}

// ---------------------------------------------------------------- launch
extern "C" void kernel_launch(void* const* d_in, const int* in_sizes, int n_in,
                              void* d_out, int out_size, void* d_ws, size_t ws_size,
                              hipStream_t stream) {
  const float* x    = (const float*)d_in[0];
  const float* fcos = (const float*)d_in[2];
  const float* fsin = (const float*)d_in[3];
  const float* wq   = (const float*)d_in[5];
  const float* wk   = (const float*)d_in[6];
  const float* wv   = (const float*)d_in[7];
  const float* wo   = (const float*)d_in[8];
  float* out = (float*)d_out;

  const size_t XN = (size_t)ROWS * DIM;
  const size_t WN = (size_t)DIM * DIM;
  u16* ws  = (u16*)d_ws;
  u16* xb  = ws;
  u16* wqb = xb + XN;
  u16* wkb = wqb + WN;
  u16* wvb = wkb + WN;
  u16* wob = wvb + WN;
  u16* q   = wob + WN;
  u16* k   = q + XN;
  u16* v   = k + XN;
  u16* ao  = v + XN;
  u16* vtg = xb;   // alias: x-bf16 dead after gemm_qkv

  const int total_chunks = (int)((XN + 4 * WN) / 4);
  cvt5_kernel<<<total_chunks / 256, 256, 0, stream>>>(x, wq, wk, wv, wo, ws);

  gemm_qkv<<<dim3(DIM / 128, ROWS / 128, 3), 256, 0, stream>>>(xb, wqb, wkb, wvb, q, k, v);

  rope_kernel<<<2 * ROWS * 1024 / 256, 256, 0, stream>>>(q, k, fcos, fsin);
  vtrans_kernel<<<dim3(SEQ / 64, BSZ * NHEADS), 256, 0, stream>>>(v, vtg);

  attn_kernel<<<dim3(512), 256, 0, stream>>>(q, k, vtg, ao);

  gemm_out<<<dim3(DIM / 128, ROWS / 128), 256, 0, stream>>>(ao, wob, out);
}